// Round 5
// baseline (5555.511 us; speedup 1.0000x reference)
//
#include <hip/hip_runtime.h>
#include <hip/hip_bf16.h>

typedef __hip_bfloat16 bf16;

#define B_ 2
#define T_ 1024
#define C_ 1024
#define H_ 16
#define N_ 64

using short8 = __attribute__((ext_vector_type(8))) short;
using f32x4 = __attribute__((ext_vector_type(4))) float;

__device__ __forceinline__ float us2f(unsigned short u) {
  return __uint_as_float(((unsigned int)u) << 16);
}
__device__ __forceinline__ bf16 f2bf(float f) { return __float2bfloat16(f); }
__device__ __forceinline__ float sigmoidf_(float x) { return 1.0f / (1.0f + expf(-x)); }
__device__ __forceinline__ float softplusf_(float x) {
  return fmaxf(x, 0.0f) + log1pf(expf(-fabsf(x)));
}

// ---------------- K0: fused weight fp32->bf16 conversion --------------------
__global__ __launch_bounds__(256) void cvt_weights_kernel(
    const float* __restrict__ s0, const float* __restrict__ s1,
    const float* __restrict__ s2, const float* __restrict__ s3,
    const float* __restrict__ s4, const float* __restrict__ s5,
    const float* __restrict__ s6,
    bf16* __restrict__ d0, bf16* __restrict__ d1, bf16* __restrict__ d2,
    bf16* __restrict__ d3, bf16* __restrict__ d4, bf16* __restrict__ d5,
    bf16* __restrict__ d6) {
  long i4 = (long)blockIdx.x * 256 + threadIdx.x;
  const float* s; bf16* d; long off;
  if (i4 < 32768) { s = s0; d = d0; off = i4; }
  else if (i4 < 294912) { s = s1; d = d1; off = i4 - 32768; }
  else if (i4 < 327680) { s = s2; d = d2; off = i4 - 294912; }
  else if (i4 < 360448) { s = s3; d = d3; off = i4 - 327680; }
  else if (i4 < 622592) { s = s4; d = d4; off = i4 - 360448; }
  else if (i4 < 884736) { s = s5; d = d5; off = i4 - 622592; }
  else { s = s6; d = d6; off = i4 - 884736; }
  float4 v = *(const float4*)(s + off * 4);
  d[off * 4 + 0] = f2bf(v.x);
  d[off * 4 + 1] = f2bf(v.y);
  d[off * 4 + 2] = f2bf(v.z);
  d[off * 4 + 3] = f2bf(v.w);
}

// ---------------- K1: token shift (writes xx f32, xxx bf16) -----------------
__global__ __launch_bounds__(256) void shift_kernel(
    const float* __restrict__ x, const float* __restrict__ tmx,
    float* __restrict__ xx, bf16* __restrict__ xxxb) {
  long idx = (long)blockIdx.x * 256 + threadIdx.x;  // < B*T*C
  int c = (int)(idx & (C_ - 1));
  int t = (int)((idx >> 10) & (T_ - 1));
  float xv = x[idx];
  float xp = (t > 0) ? x[idx - C_] : 0.0f;
  float d = xp - xv;
  xx[idx] = d;
  xxxb[idx] = f2bf(xv + d * tmx[c]);
}

// ---------------- MFMA GEMM: C = A(bf16 MxK) * W^T (W bf16 NxK) -------------
// 64x64 block tile, 4 waves; BK=64 per barrier pair (2 MFMA k-steps).
__global__ __launch_bounds__(256) void gemm_mfma_kernel(
    const bf16* __restrict__ A, const bf16* __restrict__ W,
    float* __restrict__ Cf, bf16* __restrict__ Cb,
    int M, int N, int K, int act) {
  __shared__ __align__(16) bf16 As[64][72];  // 144B row stride, 16B aligned
  __shared__ __align__(16) bf16 Ws[64][72];
  int tid = threadIdx.x;
  int m0 = blockIdx.y << 6, n0 = blockIdx.x << 6;
  int srow = tid >> 2, skg = (tid & 3) << 4;   // staging: row, 16 bf16 per thread
  int wv = tid >> 6, lane = tid & 63;
  int fr = lane & 15, fq = lane >> 4;
  f32x4 acc0 = {0.f, 0.f, 0.f, 0.f}, acc1 = acc0, acc2 = acc0, acc3 = acc0;
  const bf16* Ap = A + (long)(m0 + srow) * K + skg;
  const bf16* Wp = W + (long)(n0 + srow) * K + skg;
  for (int k0 = 0; k0 < K; k0 += 64) {
    *(short8*)&As[srow][skg] = *(const short8*)(Ap + k0);
    *(short8*)&As[srow][skg + 8] = *(const short8*)(Ap + k0 + 8);
    *(short8*)&Ws[srow][skg] = *(const short8*)(Wp + k0);
    *(short8*)&Ws[srow][skg + 8] = *(const short8*)(Wp + k0 + 8);
    __syncthreads();
#pragma unroll
    for (int kk = 0; kk < 2; kk++) {
      int ko = (fq << 3) + (kk << 5);
      short8 af = *(const short8*)&As[(wv << 4) + fr][ko];
      short8 b0 = *(const short8*)&Ws[fr][ko];
      short8 b1 = *(const short8*)&Ws[16 + fr][ko];
      short8 b2 = *(const short8*)&Ws[32 + fr][ko];
      short8 b3 = *(const short8*)&Ws[48 + fr][ko];
      acc0 = __builtin_amdgcn_mfma_f32_16x16x32_bf16(af, b0, acc0, 0, 0, 0);
      acc1 = __builtin_amdgcn_mfma_f32_16x16x32_bf16(af, b1, acc1, 0, 0, 0);
      acc2 = __builtin_amdgcn_mfma_f32_16x16x32_bf16(af, b2, acc2, 0, 0, 0);
      acc3 = __builtin_amdgcn_mfma_f32_16x16x32_bf16(af, b3, acc3, 0, 0, 0);
    }
    __syncthreads();
  }
  // C/D layout: col = lane&15, row = (lane>>4)*4 + reg
  int orow = m0 + (wv << 4) + (fq << 2);
  int ocol = n0 + fr;
  f32x4 av[4] = {acc0, acc1, acc2, acc3};
#pragma unroll
  for (int nt = 0; nt < 4; nt++) {
#pragma unroll
    for (int r = 0; r < 4; r++) {
      float vvv = av[nt][r];
      if (act == 1) vvv = tanhf(vvv);
      long oi = (long)(orow + r) * N + ocol + (nt << 4);
      if (Cb) Cb[oi] = f2bf(vvv); else Cf[oi] = vvv;
    }
  }
}

// ---------------- small fp32 GEMM (N<=64): C = A(bf16) * W^T(fp32) ----------
__global__ __launch_bounds__(256) void gemm_kernel(
    const bf16* __restrict__ A, const float* __restrict__ W,
    float* __restrict__ Cf, int M, int N, int K, int act) {
  __shared__ __align__(16) float As[16][72];
  __shared__ __align__(16) float Ws[16][72];
  int tid = threadIdx.x;
  int tx = tid & 15, ty = tid >> 4;
  int m0 = blockIdx.y * 64, n0 = blockIdx.x * 64;
  int lr = tid >> 2;
  int lc = (tid & 3) << 2;
  float acc[4][4] = {};
  for (int k0 = 0; k0 < K; k0 += 16) {
    ushort4 ua = *(const ushort4*)(A + (long)(m0 + lr) * K + (k0 + lc));
    As[lc + 0][lr] = us2f(ua.x); As[lc + 1][lr] = us2f(ua.y);
    As[lc + 2][lr] = us2f(ua.z); As[lc + 3][lr] = us2f(ua.w);
    float4 wv = make_float4(0.f, 0.f, 0.f, 0.f);
    int wr = n0 + lr;
    if (wr < N) wv = *(const float4*)(W + (long)wr * K + (k0 + lc));
    Ws[lc + 0][lr] = wv.x; Ws[lc + 1][lr] = wv.y;
    Ws[lc + 2][lr] = wv.z; Ws[lc + 3][lr] = wv.w;
    __syncthreads();
#pragma unroll
    for (int kk = 0; kk < 16; kk++) {
      float4 a4 = *(const float4*)&As[kk][ty << 2];
      float4 b4 = *(const float4*)&Ws[kk][tx << 2];
      float aa[4] = {a4.x, a4.y, a4.z, a4.w};
      float bb[4] = {b4.x, b4.y, b4.z, b4.w};
#pragma unroll
      for (int i = 0; i < 4; i++) {
#pragma unroll
        for (int j = 0; j < 4; j++) acc[i][j] += aa[i] * bb[j];
      }
    }
    __syncthreads();
  }
#pragma unroll
  for (int i = 0; i < 4; i++) {
    int row = m0 + (ty << 2) + i;
#pragma unroll
    for (int j = 0; j < 4; j++) {
      int col = n0 + (tx << 2) + j;
      if (col < N) {
        float vv = acc[i][j];
        if (act == 1) vv = tanhf(vv);
        Cf[(long)row * N + col] = vv;
      }
    }
  }
}

// ---------------- K3: deltas + build xrg/xwa/xk/xv (bf16 out) ---------------
__global__ __launch_bounds__(256) void mix4_kernel(
    const float* __restrict__ x, const float* __restrict__ xx,
    const float* __restrict__ mix, const float* __restrict__ tmaa,
    const float* __restrict__ w2,
    bf16* __restrict__ xrg, bf16* __restrict__ xwa,
    bf16* __restrict__ xk, bf16* __restrict__ xv) {
  int m = blockIdx.x;
  int tid = threadIdx.x;
  __shared__ float mrow[128];
  if (tid < 128) mrow[tid] = mix[(long)m * 128 + tid];
  __syncthreads();
#pragma unroll
  for (int cc = 0; cc < 4; cc++) {
    int c = tid + (cc << 8);
    long off = (long)m * C_ + c;
    float xb = x[off];
    float xxv = xx[off];
    float res[4];
#pragma unroll
    for (int f = 0; f < 4; f++) {
      const float4* wp = (const float4*)(w2 + (((long)f * C_ + c) << 5));
      float dl = 0.f;
#pragma unroll
      for (int d4 = 0; d4 < 8; d4++) {
        float4 u = wp[d4];
        int db = (f << 5) + (d4 << 2);
        dl += mrow[db + 0] * u.x + mrow[db + 1] * u.y +
              mrow[db + 2] * u.z + mrow[db + 3] * u.w;
      }
      res[f] = xb + xxv * (tmaa[f * C_ + c] + dl);
    }
    xrg[off] = f2bf(res[0]); xwa[off] = f2bf(res[1]);
    xk[off] = f2bf(res[2]); xv[off] = f2bf(res[3]);
  }
}

// ---------------- K5: stage-2 small GEMMs + gates + per-head kk norm --------
__global__ __launch_bounds__(256) void fuse2_kernel(
    const float* __restrict__ kraw, const float* __restrict__ w1b,
    const float* __restrict__ kk1, const float* __restrict__ a1,
    const float* __restrict__ ma1, const float* __restrict__ mk1,
    const float* __restrict__ dw2, const float* __restrict__ kkw2,
    const float* __restrict__ aw2, const float* __restrict__ maw2,
    const float* __restrict__ mkw2,
    const float* __restrict__ tdec, const float* __restrict__ taa,
    const float* __restrict__ tma, const float* __restrict__ tmk,
    float* __restrict__ ew, float* __restrict__ kfin,
    float* __restrict__ kkn, float* __restrict__ bbo) {
  int m = blockIdx.x, tid = threadIdx.x;
  __shared__ float w1r[64], kk1r[16], a1r[16], ma1r[16], mk1r[16];
  if (tid < 64) w1r[tid] = w1b[(long)m * 64 + tid];
  else if (tid < 80) kk1r[tid - 64] = kk1[(long)m * 16 + tid - 64];
  else if (tid < 96) a1r[tid - 80] = a1[(long)m * 16 + tid - 80];
  else if (tid < 112) ma1r[tid - 96] = ma1[(long)m * 16 + tid - 96];
  else if (tid < 128) mk1r[tid - 112] = mk1[(long)m * 16 + tid - 112];
  __syncthreads();
  float kkp[4], av[4], wv[4], kr[4], mkv[4];
  float sumsq = 0.f;
#pragma unroll
  for (int j = 0; j < 4; j++) {
    int c = (tid << 2) + j;
    long off = (long)m * C_ + c;
    float wd = 0.f;
    const float4* dp = (const float4*)(dw2 + ((long)c << 6));
#pragma unroll
    for (int d4 = 0; d4 < 16; d4++) {
      float4 u = dp[d4];
      int db = d4 << 2;
      wd += w1r[db + 0] * u.x + w1r[db + 1] * u.y +
            w1r[db + 2] * u.z + w1r[db + 3] * u.w;
    }
    float w = -softplusf_(-(tdec[c] + wd)) - 0.5f;
    wv[j] = w;
    float kd = 0.f, ad = 0.f, mad = 0.f, mkd = 0.f;
    const float4* kp = (const float4*)(kkw2 + ((long)c << 4));
    const float4* ap = (const float4*)(aw2 + ((long)c << 4));
    const float4* mp = (const float4*)(maw2 + ((long)c << 4));
    const float4* qp = (const float4*)(mkw2 + ((long)c << 4));
#pragma unroll
    for (int d4 = 0; d4 < 4; d4++) {
      float4 u1 = kp[d4], u2 = ap[d4], u3 = mp[d4], u4 = qp[d4];
      int db = d4 << 2;
      kd += kk1r[db + 0] * u1.x + kk1r[db + 1] * u1.y +
            kk1r[db + 2] * u1.z + kk1r[db + 3] * u1.w;
      ad += a1r[db + 0] * u2.x + a1r[db + 1] * u2.y +
            a1r[db + 2] * u2.z + a1r[db + 3] * u2.w;
      mad += ma1r[db + 0] * u3.x + ma1r[db + 1] * u3.y +
             ma1r[db + 2] * u3.z + ma1r[db + 3] * u3.w;
      mkd += mk1r[db + 0] * u4.x + mk1r[db + 1] * u4.y +
             mk1r[db + 2] * u4.z + mk1r[db + 3] * u4.w;
    }
    float krw = kraw[off];
    float kkpre = krw + kd;
    kkp[j] = kkpre;
    sumsq += kkpre * kkpre;
    float a = sigmoidf_(taa[c] + ad);
    av[j] = a;
    float ma = sigmoidf_(tma[c] + mad);
    float mk = sigmoidf_(tmk[c] + mkd);
    mkv[j] = mk;
    kr[j] = krw * (ma + a * (1.f - ma));
  }
  sumsq += __shfl_xor(sumsq, 1);
  sumsq += __shfl_xor(sumsq, 2);
  sumsq += __shfl_xor(sumsq, 4);
  sumsq += __shfl_xor(sumsq, 8);
  float rn = 1.0f / fmaxf(sqrtf(sumsq), 1e-12f);
#pragma unroll
  for (int j = 0; j < 4; j++) {
    int c = (tid << 2) + j;
    long off = (long)m * C_ + c;
    float kknv = kkp[j] * rn;
    kkn[off] = kknv;
    bbo[off] = -kknv * av[j];
    ew[off] = expf(wv[j]);
    kfin[off] = kr[j] * expf(wv[j] * mkv[j]);
  }
}

// ---------------- K6: RWKV-7 scan, wave-packed ------------------------------
// 32 blocks x 1024 threads = 16 waves/block = 4 waves/SIMD (latency cross-hide).
// block = (b,h); wave = row-block of 4 rows; lane=(g<<4)|q: row=wave*4+g,
// keys 4q..4q+3. One pass/step: 8 shfl levels on the critical chain.
__global__ __launch_bounds__(1024, 4) void scan_kernel(
    const float* __restrict__ rB, const float* __restrict__ ewB,
    const float* __restrict__ kB, const float* __restrict__ vB,
    const float* __restrict__ kkB, const float* __restrict__ bbB,
    float* __restrict__ yB) {
  int bh = blockIdx.x;
  int b = bh >> 4, h = bh & 15;
  int wave = threadIdx.x >> 6;
  int lane = threadIdx.x & 63;
  int g = lane >> 4, q = lane & 15;
  int row = (wave << 2) + g;
  int kq = q << 2;
  float S[4] = {0, 0, 0, 0};
  const long base = ((long)b * T_) * C_ + (h << 6);
  float4 skk[4], sr[4], sew[4], sk[4], sbb[4];
  float sv[4];
#pragma unroll
  for (int i = 0; i < 4; i++) {
    long o = base + (long)i * C_;
    skk[i] = *(const float4*)(kkB + o + kq);
    sr[i] = *(const float4*)(rB + o + kq);
    sew[i] = *(const float4*)(ewB + o + kq);
    sk[i] = *(const float4*)(kB + o + kq);
    sbb[i] = *(const float4*)(bbB + o + kq);
    sv[i] = vB[o + row];
  }
  for (int t = 0; t < T_; t += 4) {
#pragma unroll
    for (int i = 0; i < 4; i++) {
      int tt = t + i;
      float4 ckk = skk[i], cr = sr[i], cew = sew[i], ck = sk[i], cbb = sbb[i];
      float cv = sv[i];
      int tl = tt + 4; if (tl > T_ - 1) tl = T_ - 1;
      long o = base + (long)tl * C_;
      skk[i] = *(const float4*)(kkB + o + kq);
      sr[i] = *(const float4*)(rB + o + kq);
      sew[i] = *(const float4*)(ewB + o + kq);
      sk[i] = *(const float4*)(kB + o + kq);
      sbb[i] = *(const float4*)(bbB + o + kq);
      sv[i] = vB[o + row];
      float sab = S[0] * ckk.x + S[1] * ckk.y + S[2] * ckk.z + S[3] * ckk.w;
      sab += __shfl_xor(sab, 1); sab += __shfl_xor(sab, 2);
      sab += __shfl_xor(sab, 4); sab += __shfl_xor(sab, 8);
      S[0] = S[0] * cew.x + sab * cbb.x + cv * ck.x;
      S[1] = S[1] * cew.y + sab * cbb.y + cv * ck.y;
      S[2] = S[2] * cew.z + sab * cbb.z + cv * ck.z;
      S[3] = S[3] * cew.w + sab * cbb.w + cv * ck.w;
      float y = S[0] * cr.x + S[1] * cr.y + S[2] * cr.z + S[3] * cr.w;
      y += __shfl_xor(y, 1); y += __shfl_xor(y, 2);
      y += __shfl_xor(y, 4); y += __shfl_xor(y, 8);
      if (q == 0) yB[base + (long)tt * C_ + row] = y;
    }
  }
}

// ---------------- K7: GroupNorm + bonus + gate (bf16 out) -------------------
__global__ __launch_bounds__(256) void gnout_kernel(
    const float* __restrict__ y, const float* __restrict__ r,
    const float* __restrict__ kf, const float* __restrict__ v,
    const float* __restrict__ g,
    const float* __restrict__ lnw, const float* __restrict__ lnb,
    const float* __restrict__ fa, bf16* __restrict__ z) {
  int tid = threadIdx.x;
  int w = tid >> 6, lane = tid & 63;
  int gi = (blockIdx.x << 2) + w;  // (b*T+t)*H + h
  int h = gi & 15, mt = gi >> 4;
  long off = (long)mt * C_ + (h << 6) + lane;
  float yv = y[off];
  float s = yv;
  s += __shfl_xor(s, 1); s += __shfl_xor(s, 2); s += __shfl_xor(s, 4);
  s += __shfl_xor(s, 8); s += __shfl_xor(s, 16); s += __shfl_xor(s, 32);
  float mu = s * (1.0f / 64.0f);
  float d = yv - mu;
  float s2 = d * d;
  s2 += __shfl_xor(s2, 1); s2 += __shfl_xor(s2, 2); s2 += __shfl_xor(s2, 4);
  s2 += __shfl_xor(s2, 8); s2 += __shfl_xor(s2, 16); s2 += __shfl_xor(s2, 32);
  float var = s2 * (1.0f / 64.0f);
  int hc = (h << 6) + lane;
  float dot = r[off] * kf[off] * fa[hc];
  dot += __shfl_xor(dot, 1); dot += __shfl_xor(dot, 2); dot += __shfl_xor(dot, 4);
  dot += __shfl_xor(dot, 8); dot += __shfl_xor(dot, 16); dot += __shfl_xor(dot, 32);
  float yn = d * rsqrtf(var + 0.00064f) * lnw[hc] + lnb[hc];
  z[off] = f2bf((yn + dot * v[off]) * g[off]);
}

extern "C" void kernel_launch(void* const* d_in, const int* in_sizes, int n_in,
                              void* d_out, int out_size, void* d_ws, size_t ws_size,
                              hipStream_t stream) {
  const float* x = (const float*)d_in[0];
  const float* tmx = (const float*)d_in[1];
  const float* tmaa = (const float*)d_in[2];
  const float* tmw1 = (const float*)d_in[3];
  const float* tmw2 = (const float*)d_in[4];
  const float* tdec = (const float*)d_in[5];
  const float* tdw1 = (const float*)d_in[6];
  const float* tdw2 = (const float*)d_in[7];
  const float* taa5 = (const float*)d_in[8];
  const float* taw1 = (const float*)d_in[9];
  const float* taw2 = (const float*)d_in[10];
  const float* tkw1 = (const float*)d_in[11];
  const float* tkw2 = (const float*)d_in[12];
  const float* gw1 = (const float*)d_in[13];
  const float* gw2 = (const float*)d_in[14];
  const float* tmia = (const float*)d_in[15];
  const float* maw1 = (const float*)d_in[16];
  const float* maw2 = (const float*)d_in[17];
  const float* tmik = (const float*)d_in[18];
  const float* mkw1 = (const float*)d_in[19];
  const float* mkw2 = (const float*)d_in[20];
  const float* wrec = (const float*)d_in[21];
  const float* wkey = (const float*)d_in[22];
  const float* wval = (const float*)d_in[23];
  const float* wout = (const float*)d_in[24];
  const float* lnw = (const float*)d_in[25];
  const float* lnb = (const float*)d_in[26];
  const float* faaa = (const float*)d_in[27];

  const long MT = 2048, CC = 1024;
  char* base = (char*)d_ws;
  float* xx = (float*)base;    base += MT * CC * 4;   // also y
  bf16* xxxb = (bf16*)base;    base += MT * CC * 2;
  bf16* xrgb = (bf16*)base;    base += MT * CC * 2;   // ┐ kfin overlays (8MB)
  bf16* xwab = (bf16*)base;    base += MT * CC * 2;   // ┘
  bf16* xkb = (bf16*)base;     base += MT * CC * 2;   // ┐ kkn overlays (8MB)
  bf16* xvb = (bf16*)base;     base += MT * CC * 2;   // ┘
  float* rr = (float*)base;    base += MT * CC * 4;
  float* kraw = (float*)base;  base += MT * CC * 4;   // also ew
  float* vv = (float*)base;    base += MT * CC * 4;
  float* gg = (float*)base;    base += MT * CC * 4;
  float* bbo = (float*)base;   base += MT * CC * 4;
  float* mix = (float*)base;   base += MT * 128 * 4;
  bf16* g1b = (bf16*)base;     base += MT * 128 * 2;
  float* w1b = (float*)base;   base += MT * 64 * 4;
  float* kk1 = (float*)base;   base += MT * 16 * 4;
  float* a1 = (float*)base;    base += MT * 16 * 4;
  float* ma1 = (float*)base;   base += MT * 16 * 4;
  float* mk1 = (float*)base;   base += MT * 16 * 4;
  bf16* zb = (bf16*)base;      base += MT * CC * 2;
  bf16* tmw1b = (bf16*)base;   base += 128 * CC * 2;
  bf16* wrecb = (bf16*)base;   base += CC * CC * 2;
  bf16* gw1b = (bf16*)base;    base += 128 * CC * 2;
  bf16* gw2b = (bf16*)base;    base += CC * 128 * 2;
  bf16* wkeyb = (bf16*)base;   base += CC * CC * 2;
  bf16* wvalb = (bf16*)base;   base += CC * CC * 2;
  bf16* woutb = (bf16*)base;   base += CC * CC * 2;
  // aliases (dead-buffer reuse, verified non-overlapping in time):
  float* ew = kraw;            // fuse2 reads kraw then writes ew at same offs
  float* kfin = (float*)xrgb;  // xrg/xwa bf16 dead before fuse2
  float* kkn = (float*)xkb;    // xk/xv bf16 dead before fuse2
  float* y = xx;               // xx dead after mix4

  auto gemm_m = [&](const bf16* A, const bf16* W, float* Cf, bf16* Cb,
                    int M, int N, int K, int act) {
    dim3 grid(N / 64, M / 64);
    gemm_mfma_kernel<<<grid, 256, 0, stream>>>(A, W, Cf, Cb, M, N, K, act);
  };
  auto gemm_s = [&](const bf16* A, const float* W, float* Cf,
                    int M, int N, int K, int act) {
    dim3 grid((N + 63) / 64, M / 64);
    gemm_kernel<<<grid, 256, 0, stream>>>(A, W, Cf, M, N, K, act);
  };

  cvt_weights_kernel<<<4480, 256, 0, stream>>>(
      tmw1, wrec, gw1, gw2, wkey, wval, wout,
      tmw1b, wrecb, gw1b, gw2b, wkeyb, wvalb, woutb);
  shift_kernel<<<8192, 256, 0, stream>>>(x, tmx, xx, xxxb);
  gemm_m(xxxb, tmw1b, mix, nullptr, 2048, 128, 1024, 1);
  mix4_kernel<<<2048, 256, 0, stream>>>(x, xx, mix, tmaa, tmw2,
                                        xrgb, xwab, xkb, xvb);
  gemm_m(xrgb, wrecb, rr, nullptr, 2048, 1024, 1024, 0);
  gemm_m(xrgb, gw1b, nullptr, g1b, 2048, 128, 1024, 1);
  gemm_m(g1b, gw2b, gg, nullptr, 2048, 1024, 128, 0);
  gemm_m(xkb, wkeyb, kraw, nullptr, 2048, 1024, 1024, 0);
  gemm_s(xkb, tkw1, kk1, 2048, 16, 1024, 1);
  gemm_s(xkb, mkw1, mk1, 2048, 16, 1024, 0);
  gemm_m(xvb, wvalb, vv, nullptr, 2048, 1024, 1024, 0);
  gemm_s(xwab, tdw1, w1b, 2048, 64, 1024, 1);
  gemm_s(xwab, taw1, a1, 2048, 16, 1024, 0);
  gemm_s(xwab, maw1, ma1, 2048, 16, 1024, 0);
  fuse2_kernel<<<2048, 256, 0, stream>>>(kraw, w1b, kk1, a1, ma1, mk1,
                                         tdw2, tkw2, taw2, maw2, mkw2,
                                         tdec, taa5, tmia, tmik,
                                         ew, kfin, kkn, bbo);
  scan_kernel<<<32, 1024, 0, stream>>>(rr, ew, kfin, vv, kkn, bbo, y);
  gnout_kernel<<<8192, 256, 0, stream>>>(y, rr, kfin, vv, gg, lnw, lnb, faaa, zb);
  gemm_m(zb, woutb, (float*)d_out, nullptr, 2048, 1024, 1024, 0);
}

// Round 6
// 1344.165 us; speedup vs baseline: 4.1331x; 4.1331x over previous
//
#include <hip/hip_runtime.h>
#include <hip/hip_bf16.h>

typedef __hip_bfloat16 bf16;

#define B_ 2
#define T_ 1024
#define C_ 1024
#define H_ 16
#define N_ 64

using short8 = __attribute__((ext_vector_type(8))) short;
using f32x4 = __attribute__((ext_vector_type(4))) float;

__device__ __forceinline__ float us2f(unsigned short u) {
  return __uint_as_float(((unsigned int)u) << 16);
}
__device__ __forceinline__ bf16 f2bf(float f) { return __float2bfloat16(f); }
__device__ __forceinline__ float sigmoidf_(float x) { return 1.0f / (1.0f + expf(-x)); }
__device__ __forceinline__ float softplusf_(float x) {
  return fmaxf(x, 0.0f) + log1pf(expf(-fabsf(x)));
}

// ---------------- K0: fused weight fp32->bf16 conversion --------------------
__global__ __launch_bounds__(256) void cvt_weights_kernel(
    const float* __restrict__ s0, const float* __restrict__ s1,
    const float* __restrict__ s2, const float* __restrict__ s3,
    const float* __restrict__ s4, const float* __restrict__ s5,
    const float* __restrict__ s6,
    bf16* __restrict__ d0, bf16* __restrict__ d1, bf16* __restrict__ d2,
    bf16* __restrict__ d3, bf16* __restrict__ d4, bf16* __restrict__ d5,
    bf16* __restrict__ d6) {
  long i4 = (long)blockIdx.x * 256 + threadIdx.x;
  const float* s; bf16* d; long off;
  if (i4 < 32768) { s = s0; d = d0; off = i4; }
  else if (i4 < 294912) { s = s1; d = d1; off = i4 - 32768; }
  else if (i4 < 327680) { s = s2; d = d2; off = i4 - 294912; }
  else if (i4 < 360448) { s = s3; d = d3; off = i4 - 327680; }
  else if (i4 < 622592) { s = s4; d = d4; off = i4 - 360448; }
  else if (i4 < 884736) { s = s5; d = d5; off = i4 - 622592; }
  else { s = s6; d = d6; off = i4 - 884736; }
  float4 v = *(const float4*)(s + off * 4);
  d[off * 4 + 0] = f2bf(v.x);
  d[off * 4 + 1] = f2bf(v.y);
  d[off * 4 + 2] = f2bf(v.z);
  d[off * 4 + 3] = f2bf(v.w);
}

// ---------------- K1: token shift (writes xx f32, xxx bf16) -----------------
__global__ __launch_bounds__(256) void shift_kernel(
    const float* __restrict__ x, const float* __restrict__ tmx,
    float* __restrict__ xx, bf16* __restrict__ xxxb) {
  long idx = (long)blockIdx.x * 256 + threadIdx.x;  // < B*T*C
  int c = (int)(idx & (C_ - 1));
  int t = (int)((idx >> 10) & (T_ - 1));
  float xv = x[idx];
  float xp = (t > 0) ? x[idx - C_] : 0.0f;
  float d = xp - xv;
  xx[idx] = d;
  xxxb[idx] = f2bf(xv + d * tmx[c]);
}

// ---------------- MFMA GEMM: C = A(bf16 MxK) * W^T (W bf16 NxK) -------------
// 64x64 block tile, 4 waves; BK=64 per barrier pair (2 MFMA k-steps).
__global__ __launch_bounds__(256) void gemm_mfma_kernel(
    const bf16* __restrict__ A, const bf16* __restrict__ W,
    float* __restrict__ Cf, bf16* __restrict__ Cb,
    int M, int N, int K, int act) {
  __shared__ __align__(16) bf16 As[64][72];  // 144B row stride, 16B aligned
  __shared__ __align__(16) bf16 Ws[64][72];
  int tid = threadIdx.x;
  int m0 = blockIdx.y << 6, n0 = blockIdx.x << 6;
  int srow = tid >> 2, skg = (tid & 3) << 4;   // staging: row, 16 bf16 per thread
  int wv = tid >> 6, lane = tid & 63;
  int fr = lane & 15, fq = lane >> 4;
  f32x4 acc0 = {0.f, 0.f, 0.f, 0.f}, acc1 = acc0, acc2 = acc0, acc3 = acc0;
  const bf16* Ap = A + (long)(m0 + srow) * K + skg;
  const bf16* Wp = W + (long)(n0 + srow) * K + skg;
  for (int k0 = 0; k0 < K; k0 += 64) {
    *(short8*)&As[srow][skg] = *(const short8*)(Ap + k0);
    *(short8*)&As[srow][skg + 8] = *(const short8*)(Ap + k0 + 8);
    *(short8*)&Ws[srow][skg] = *(const short8*)(Wp + k0);
    *(short8*)&Ws[srow][skg + 8] = *(const short8*)(Wp + k0 + 8);
    __syncthreads();
#pragma unroll
    for (int kk = 0; kk < 2; kk++) {
      int ko = (fq << 3) + (kk << 5);
      short8 af = *(const short8*)&As[(wv << 4) + fr][ko];
      short8 b0 = *(const short8*)&Ws[fr][ko];
      short8 b1 = *(const short8*)&Ws[16 + fr][ko];
      short8 b2 = *(const short8*)&Ws[32 + fr][ko];
      short8 b3 = *(const short8*)&Ws[48 + fr][ko];
      acc0 = __builtin_amdgcn_mfma_f32_16x16x32_bf16(af, b0, acc0, 0, 0, 0);
      acc1 = __builtin_amdgcn_mfma_f32_16x16x32_bf16(af, b1, acc1, 0, 0, 0);
      acc2 = __builtin_amdgcn_mfma_f32_16x16x32_bf16(af, b2, acc2, 0, 0, 0);
      acc3 = __builtin_amdgcn_mfma_f32_16x16x32_bf16(af, b3, acc3, 0, 0, 0);
    }
    __syncthreads();
  }
  // C/D layout: col = lane&15, row = (lane>>4)*4 + reg
  int orow = m0 + (wv << 4) + (fq << 2);
  int ocol = n0 + fr;
  f32x4 av[4] = {acc0, acc1, acc2, acc3};
#pragma unroll
  for (int nt = 0; nt < 4; nt++) {
#pragma unroll
    for (int r = 0; r < 4; r++) {
      float vvv = av[nt][r];
      if (act == 1) vvv = tanhf(vvv);
      long oi = (long)(orow + r) * N + ocol + (nt << 4);
      if (Cb) Cb[oi] = f2bf(vvv); else Cf[oi] = vvv;
    }
  }
}

// ---------------- small fp32 GEMM (N<=64): C = A(bf16) * W^T(fp32) ----------
__global__ __launch_bounds__(256) void gemm_kernel(
    const bf16* __restrict__ A, const float* __restrict__ W,
    float* __restrict__ Cf, int M, int N, int K, int act) {
  __shared__ __align__(16) float As[16][72];
  __shared__ __align__(16) float Ws[16][72];
  int tid = threadIdx.x;
  int tx = tid & 15, ty = tid >> 4;
  int m0 = blockIdx.y * 64, n0 = blockIdx.x * 64;
  int lr = tid >> 2;
  int lc = (tid & 3) << 2;
  float acc[4][4] = {};
  for (int k0 = 0; k0 < K; k0 += 16) {
    ushort4 ua = *(const ushort4*)(A + (long)(m0 + lr) * K + (k0 + lc));
    As[lc + 0][lr] = us2f(ua.x); As[lc + 1][lr] = us2f(ua.y);
    As[lc + 2][lr] = us2f(ua.z); As[lc + 3][lr] = us2f(ua.w);
    float4 wv = make_float4(0.f, 0.f, 0.f, 0.f);
    int wr = n0 + lr;
    if (wr < N) wv = *(const float4*)(W + (long)wr * K + (k0 + lc));
    Ws[lc + 0][lr] = wv.x; Ws[lc + 1][lr] = wv.y;
    Ws[lc + 2][lr] = wv.z; Ws[lc + 3][lr] = wv.w;
    __syncthreads();
#pragma unroll
    for (int kk = 0; kk < 16; kk++) {
      float4 a4 = *(const float4*)&As[kk][ty << 2];
      float4 b4 = *(const float4*)&Ws[kk][tx << 2];
      float aa[4] = {a4.x, a4.y, a4.z, a4.w};
      float bb[4] = {b4.x, b4.y, b4.z, b4.w};
#pragma unroll
      for (int i = 0; i < 4; i++) {
#pragma unroll
        for (int j = 0; j < 4; j++) acc[i][j] += aa[i] * bb[j];
      }
    }
    __syncthreads();
  }
#pragma unroll
  for (int i = 0; i < 4; i++) {
    int row = m0 + (ty << 2) + i;
#pragma unroll
    for (int j = 0; j < 4; j++) {
      int col = n0 + (tx << 2) + j;
      if (col < N) {
        float vv = acc[i][j];
        if (act == 1) vv = tanhf(vv);
        Cf[(long)row * N + col] = vv;
      }
    }
  }
}

// ---------------- K3: deltas + build xrg/xwa/xk/xv (bf16 out) ---------------
__global__ __launch_bounds__(256) void mix4_kernel(
    const float* __restrict__ x, const float* __restrict__ xx,
    const float* __restrict__ mix, const float* __restrict__ tmaa,
    const float* __restrict__ w2,
    bf16* __restrict__ xrg, bf16* __restrict__ xwa,
    bf16* __restrict__ xk, bf16* __restrict__ xv) {
  int m = blockIdx.x;
  int tid = threadIdx.x;
  __shared__ float mrow[128];
  if (tid < 128) mrow[tid] = mix[(long)m * 128 + tid];
  __syncthreads();
#pragma unroll
  for (int cc = 0; cc < 4; cc++) {
    int c = tid + (cc << 8);
    long off = (long)m * C_ + c;
    float xb = x[off];
    float xxv = xx[off];
    float res[4];
#pragma unroll
    for (int f = 0; f < 4; f++) {
      const float4* wp = (const float4*)(w2 + (((long)f * C_ + c) << 5));
      float dl = 0.f;
#pragma unroll
      for (int d4 = 0; d4 < 8; d4++) {
        float4 u = wp[d4];
        int db = (f << 5) + (d4 << 2);
        dl += mrow[db + 0] * u.x + mrow[db + 1] * u.y +
              mrow[db + 2] * u.z + mrow[db + 3] * u.w;
      }
      res[f] = xb + xxv * (tmaa[f * C_ + c] + dl);
    }
    xrg[off] = f2bf(res[0]); xwa[off] = f2bf(res[1]);
    xk[off] = f2bf(res[2]); xv[off] = f2bf(res[3]);
  }
}

// ---------------- K5: stage-2 small GEMMs + gates + per-head kk norm --------
__global__ __launch_bounds__(256) void fuse2_kernel(
    const float* __restrict__ kraw, const float* __restrict__ w1b,
    const float* __restrict__ kk1, const float* __restrict__ a1,
    const float* __restrict__ ma1, const float* __restrict__ mk1,
    const float* __restrict__ dw2, const float* __restrict__ kkw2,
    const float* __restrict__ aw2, const float* __restrict__ maw2,
    const float* __restrict__ mkw2,
    const float* __restrict__ tdec, const float* __restrict__ taa,
    const float* __restrict__ tma, const float* __restrict__ tmk,
    float* __restrict__ ew, float* __restrict__ kfin,
    float* __restrict__ kkn, float* __restrict__ bbo) {
  int m = blockIdx.x, tid = threadIdx.x;
  __shared__ float w1r[64], kk1r[16], a1r[16], ma1r[16], mk1r[16];
  if (tid < 64) w1r[tid] = w1b[(long)m * 64 + tid];
  else if (tid < 80) kk1r[tid - 64] = kk1[(long)m * 16 + tid - 64];
  else if (tid < 96) a1r[tid - 80] = a1[(long)m * 16 + tid - 80];
  else if (tid < 112) ma1r[tid - 96] = ma1[(long)m * 16 + tid - 96];
  else if (tid < 128) mk1r[tid - 112] = mk1[(long)m * 16 + tid - 112];
  __syncthreads();
  float kkp[4], av[4], wv[4], kr[4], mkv[4];
  float sumsq = 0.f;
#pragma unroll
  for (int j = 0; j < 4; j++) {
    int c = (tid << 2) + j;
    long off = (long)m * C_ + c;
    float wd = 0.f;
    const float4* dp = (const float4*)(dw2 + ((long)c << 6));
#pragma unroll
    for (int d4 = 0; d4 < 16; d4++) {
      float4 u = dp[d4];
      int db = d4 << 2;
      wd += w1r[db + 0] * u.x + w1r[db + 1] * u.y +
            w1r[db + 2] * u.z + w1r[db + 3] * u.w;
    }
    float w = -softplusf_(-(tdec[c] + wd)) - 0.5f;
    wv[j] = w;
    float kd = 0.f, ad = 0.f, mad = 0.f, mkd = 0.f;
    const float4* kp = (const float4*)(kkw2 + ((long)c << 4));
    const float4* ap = (const float4*)(aw2 + ((long)c << 4));
    const float4* mp = (const float4*)(maw2 + ((long)c << 4));
    const float4* qp = (const float4*)(mkw2 + ((long)c << 4));
#pragma unroll
    for (int d4 = 0; d4 < 4; d4++) {
      float4 u1 = kp[d4], u2 = ap[d4], u3 = mp[d4], u4 = qp[d4];
      int db = d4 << 2;
      kd += kk1r[db + 0] * u1.x + kk1r[db + 1] * u1.y +
            kk1r[db + 2] * u1.z + kk1r[db + 3] * u1.w;
      ad += a1r[db + 0] * u2.x + a1r[db + 1] * u2.y +
            a1r[db + 2] * u2.z + a1r[db + 3] * u2.w;
      mad += ma1r[db + 0] * u3.x + ma1r[db + 1] * u3.y +
             ma1r[db + 2] * u3.z + ma1r[db + 3] * u3.w;
      mkd += mk1r[db + 0] * u4.x + mk1r[db + 1] * u4.y +
             mk1r[db + 2] * u4.z + mk1r[db + 3] * u4.w;
    }
    float krw = kraw[off];
    float kkpre = krw + kd;
    kkp[j] = kkpre;
    sumsq += kkpre * kkpre;
    float a = sigmoidf_(taa[c] + ad);
    av[j] = a;
    float ma = sigmoidf_(tma[c] + mad);
    float mk = sigmoidf_(tmk[c] + mkd);
    mkv[j] = mk;
    kr[j] = krw * (ma + a * (1.f - ma));
  }
  sumsq += __shfl_xor(sumsq, 1);
  sumsq += __shfl_xor(sumsq, 2);
  sumsq += __shfl_xor(sumsq, 4);
  sumsq += __shfl_xor(sumsq, 8);
  float rn = 1.0f / fmaxf(sqrtf(sumsq), 1e-12f);
#pragma unroll
  for (int j = 0; j < 4; j++) {
    int c = (tid << 2) + j;
    long off = (long)m * C_ + c;
    float kknv = kkp[j] * rn;
    kkn[off] = kknv;
    bbo[off] = -kknv * av[j];
    ew[off] = expf(wv[j]);
    kfin[off] = kr[j] * expf(wv[j] * mkv[j]);
  }
}

// ---------------- K6: RWKV-7 scan, 64 blocks x 512 threads ------------------
// 512 waves: (b,h) x 16 row-blocks of 4 rows. Block = (bh, half): 8 waves.
// lane=(g<<4)|q: row=wave*4+g, keys 4q..4q+3. y-reduction of step t-1 is
// interleaved into the sab shfl chain of step t (latency shadow).
__global__ __launch_bounds__(512) void scan_kernel(
    const float* __restrict__ rB, const float* __restrict__ ewB,
    const float* __restrict__ kB, const float* __restrict__ vB,
    const float* __restrict__ kkB, const float* __restrict__ bbB,
    float* __restrict__ yB) {
  int bid = blockIdx.x;              // 64
  int bh = bid >> 1;
  int b = bh >> 4, h = bh & 15;
  int wave = ((bid & 1) << 3) + (threadIdx.x >> 6);  // 0..15
  int lane = threadIdx.x & 63;
  int g = lane >> 4, q = lane & 15;
  int row = (wave << 2) + g;
  int kq = q << 2;
  float S0 = 0.f, S1 = 0.f, S2 = 0.f, S3 = 0.f;
  const long base = ((long)b * T_) * C_ + (h << 6);
  float4 skk[4], sr[4], sew[4], sk[4], sbb[4];
  float sv[4];
#pragma unroll
  for (int i = 0; i < 4; i++) {
    long o = base + (long)i * C_;
    skk[i] = *(const float4*)(kkB + o + kq);
    sr[i] = *(const float4*)(rB + o + kq);
    sew[i] = *(const float4*)(ewB + o + kq);
    sk[i] = *(const float4*)(kB + o + kq);
    sbb[i] = *(const float4*)(bbB + o + kq);
    sv[i] = vB[o + row];
  }
  float yp = 0.f;       // pending partial y from previous step
  long ypoff = 0;
  for (int t = 0; t < T_; t += 4) {
#pragma unroll
    for (int i = 0; i < 4; i++) {
      int tt = t + i;
      float4 ckk = skk[i], cr = sr[i], cew = sew[i], ck = sk[i], cbb = sbb[i];
      float cv = sv[i];
      int tl = tt + 4; if (tl > T_ - 1) tl = T_ - 1;
      long o = base + (long)tl * C_;
      skk[i] = *(const float4*)(kkB + o + kq);
      sr[i] = *(const float4*)(rB + o + kq);
      sew[i] = *(const float4*)(ewB + o + kq);
      sk[i] = *(const float4*)(kB + o + kq);
      sbb[i] = *(const float4*)(bbB + o + kq);
      sv[i] = vB[o + row];
      // interleaved reductions: sab (critical) + yp (previous step's y)
      float sab = S0 * ckk.x + S1 * ckk.y + S2 * ckk.z + S3 * ckk.w;
      float u1 = __shfl_xor(sab, 1); float w1 = __shfl_xor(yp, 1);
      sab += u1; yp += w1;
      float u2 = __shfl_xor(sab, 2); float w2 = __shfl_xor(yp, 2);
      sab += u2; yp += w2;
      float u4 = __shfl_xor(sab, 4); float w4 = __shfl_xor(yp, 4);
      sab += u4; yp += w4;
      float u8 = __shfl_xor(sab, 8); float w8 = __shfl_xor(yp, 8);
      sab += u8; yp += w8;
      if (q == 0 && tt > 0) yB[ypoff + row] = yp;
      S0 = S0 * cew.x + sab * cbb.x + cv * ck.x;
      S1 = S1 * cew.y + sab * cbb.y + cv * ck.y;
      S2 = S2 * cew.z + sab * cbb.z + cv * ck.z;
      S3 = S3 * cew.w + sab * cbb.w + cv * ck.w;
      yp = S0 * cr.x + S1 * cr.y + S2 * cr.z + S3 * cr.w;
      ypoff = base + (long)tt * C_;
    }
  }
  yp += __shfl_xor(yp, 1); yp += __shfl_xor(yp, 2);
  yp += __shfl_xor(yp, 4); yp += __shfl_xor(yp, 8);
  if (q == 0) yB[ypoff + row] = yp;
}

// ---------------- K7: GroupNorm + bonus + gate (bf16 out) -------------------
__global__ __launch_bounds__(256) void gnout_kernel(
    const float* __restrict__ y, const float* __restrict__ r,
    const float* __restrict__ kf, const float* __restrict__ v,
    const float* __restrict__ g,
    const float* __restrict__ lnw, const float* __restrict__ lnb,
    const float* __restrict__ fa, bf16* __restrict__ z) {
  int tid = threadIdx.x;
  int w = tid >> 6, lane = tid & 63;
  int gi = (blockIdx.x << 2) + w;  // (b*T+t)*H + h
  int h = gi & 15, mt = gi >> 4;
  long off = (long)mt * C_ + (h << 6) + lane;
  float yv = y[off];
  float s = yv;
  s += __shfl_xor(s, 1); s += __shfl_xor(s, 2); s += __shfl_xor(s, 4);
  s += __shfl_xor(s, 8); s += __shfl_xor(s, 16); s += __shfl_xor(s, 32);
  float mu = s * (1.0f / 64.0f);
  float d = yv - mu;
  float s2 = d * d;
  s2 += __shfl_xor(s2, 1); s2 += __shfl_xor(s2, 2); s2 += __shfl_xor(s2, 4);
  s2 += __shfl_xor(s2, 8); s2 += __shfl_xor(s2, 16); s2 += __shfl_xor(s2, 32);
  float var = s2 * (1.0f / 64.0f);
  int hc = (h << 6) + lane;
  float dot = r[off] * kf[off] * fa[hc];
  dot += __shfl_xor(dot, 1); dot += __shfl_xor(dot, 2); dot += __shfl_xor(dot, 4);
  dot += __shfl_xor(dot, 8); dot += __shfl_xor(dot, 16); dot += __shfl_xor(dot, 32);
  float yn = d * rsqrtf(var + 0.00064f) * lnw[hc] + lnb[hc];
  z[off] = f2bf((yn + dot * v[off]) * g[off]);
}

extern "C" void kernel_launch(void* const* d_in, const int* in_sizes, int n_in,
                              void* d_out, int out_size, void* d_ws, size_t ws_size,
                              hipStream_t stream) {
  const float* x = (const float*)d_in[0];
  const float* tmx = (const float*)d_in[1];
  const float* tmaa = (const float*)d_in[2];
  const float* tmw1 = (const float*)d_in[3];
  const float* tmw2 = (const float*)d_in[4];
  const float* tdec = (const float*)d_in[5];
  const float* tdw1 = (const float*)d_in[6];
  const float* tdw2 = (const float*)d_in[7];
  const float* taa5 = (const float*)d_in[8];
  const float* taw1 = (const float*)d_in[9];
  const float* taw2 = (const float*)d_in[10];
  const float* tkw1 = (const float*)d_in[11];
  const float* tkw2 = (const float*)d_in[12];
  const float* gw1 = (const float*)d_in[13];
  const float* gw2 = (const float*)d_in[14];
  const float* tmia = (const float*)d_in[15];
  const float* maw1 = (const float*)d_in[16];
  const float* maw2 = (const float*)d_in[17];
  const float* tmik = (const float*)d_in[18];
  const float* mkw1 = (const float*)d_in[19];
  const float* mkw2 = (const float*)d_in[20];
  const float* wrec = (const float*)d_in[21];
  const float* wkey = (const float*)d_in[22];
  const float* wval = (const float*)d_in[23];
  const float* wout = (const float*)d_in[24];
  const float* lnw = (const float*)d_in[25];
  const float* lnb = (const float*)d_in[26];
  const float* faaa = (const float*)d_in[27];

  const long MT = 2048, CC = 1024;
  char* base = (char*)d_ws;
  float* xx = (float*)base;    base += MT * CC * 4;   // also y
  bf16* xxxb = (bf16*)base;    base += MT * CC * 2;
  bf16* xrgb = (bf16*)base;    base += MT * CC * 2;   // ┐ kfin overlays (8MB)
  bf16* xwab = (bf16*)base;    base += MT * CC * 2;   // ┘
  bf16* xkb = (bf16*)base;     base += MT * CC * 2;   // ┐ kkn overlays (8MB)
  bf16* xvb = (bf16*)base;     base += MT * CC * 2;   // ┘
  float* rr = (float*)base;    base += MT * CC * 4;
  float* kraw = (float*)base;  base += MT * CC * 4;   // also ew
  float* vv = (float*)base;    base += MT * CC * 4;
  float* gg = (float*)base;    base += MT * CC * 4;
  float* bbo = (float*)base;   base += MT * CC * 4;
  float* mix = (float*)base;   base += MT * 128 * 4;
  bf16* g1b = (bf16*)base;     base += MT * 128 * 2;
  float* w1b = (float*)base;   base += MT * 64 * 4;
  float* kk1 = (float*)base;   base += MT * 16 * 4;
  float* a1 = (float*)base;    base += MT * 16 * 4;
  float* ma1 = (float*)base;   base += MT * 16 * 4;
  float* mk1 = (float*)base;   base += MT * 16 * 4;
  bf16* zb = (bf16*)base;      base += MT * CC * 2;
  bf16* tmw1b = (bf16*)base;   base += 128 * CC * 2;
  bf16* wrecb = (bf16*)base;   base += CC * CC * 2;
  bf16* gw1b = (bf16*)base;    base += 128 * CC * 2;
  bf16* gw2b = (bf16*)base;    base += CC * 128 * 2;
  bf16* wkeyb = (bf16*)base;   base += CC * CC * 2;
  bf16* wvalb = (bf16*)base;   base += CC * CC * 2;
  bf16* woutb = (bf16*)base;   base += CC * CC * 2;
  // aliases (dead-buffer reuse, verified non-overlapping in time):
  float* ew = kraw;            // fuse2 reads kraw then writes ew at same offs
  float* kfin = (float*)xrgb;  // xrg/xwa bf16 dead before fuse2
  float* kkn = (float*)xkb;    // xk/xv bf16 dead before fuse2
  float* y = xx;               // xx dead after mix4

  auto gemm_m = [&](const bf16* A, const bf16* W, float* Cf, bf16* Cb,
                    int M, int N, int K, int act) {
    dim3 grid(N / 64, M / 64);
    gemm_mfma_kernel<<<grid, 256, 0, stream>>>(A, W, Cf, Cb, M, N, K, act);
  };
  auto gemm_s = [&](const bf16* A, const float* W, float* Cf,
                    int M, int N, int K, int act) {
    dim3 grid((N + 63) / 64, M / 64);
    gemm_kernel<<<grid, 256, 0, stream>>>(A, W, Cf, M, N, K, act);
  };

  cvt_weights_kernel<<<4480, 256, 0, stream>>>(
      tmw1, wrec, gw1, gw2, wkey, wval, wout,
      tmw1b, wrecb, gw1b, gw2b, wkeyb, wvalb, woutb);
  shift_kernel<<<8192, 256, 0, stream>>>(x, tmx, xx, xxxb);
  gemm_m(xxxb, tmw1b, mix, nullptr, 2048, 128, 1024, 1);
  mix4_kernel<<<2048, 256, 0, stream>>>(x, xx, mix, tmaa, tmw2,
                                        xrgb, xwab, xkb, xvb);
  gemm_m(xrgb, wrecb, rr, nullptr, 2048, 1024, 1024, 0);
  gemm_m(xrgb, gw1b, nullptr, g1b, 2048, 128, 1024, 1);
  gemm_m(g1b, gw2b, gg, nullptr, 2048, 1024, 128, 0);
  gemm_m(xkb, wkeyb, kraw, nullptr, 2048, 1024, 1024, 0);
  gemm_s(xkb, tkw1, kk1, 2048, 16, 1024, 1);
  gemm_s(xkb, mkw1, mk1, 2048, 16, 1024, 0);
  gemm_m(xvb, wvalb, vv, nullptr, 2048, 1024, 1024, 0);
  gemm_s(xwab, tdw1, w1b, 2048, 64, 1024, 1);
  gemm_s(xwab, taw1, a1, 2048, 16, 1024, 0);
  gemm_s(xwab, maw1, ma1, 2048, 16, 1024, 0);
  fuse2_kernel<<<2048, 256, 0, stream>>>(kraw, w1b, kk1, a1, ma1, mk1,
                                         tdw2, tkw2, taw2, maw2, mkw2,
                                         tdec, taa5, tmia, tmik,
                                         ew, kfin, kkn, bbo);
  scan_kernel<<<64, 512, 0, stream>>>(rr, ew, kfin, vv, kkn, bbo, y);
  gnout_kernel<<<8192, 256, 0, stream>>>(y, rr, kfin, vv, gg, lnw, lnb, faaa, zb);
  gemm_m(zb, woutb, (float*)d_out, nullptr, 2048, 1024, 1024, 0);
}

// Round 7
// 1108.263 us; speedup vs baseline: 5.0128x; 1.2129x over previous
//
#include <hip/hip_runtime.h>
#include <hip/hip_bf16.h>

typedef __hip_bfloat16 bf16;

#define B_ 2
#define T_ 1024
#define C_ 1024
#define H_ 16
#define N_ 64

using short8 = __attribute__((ext_vector_type(8))) short;
using f32x4 = __attribute__((ext_vector_type(4))) float;

__device__ __forceinline__ float us2f(unsigned short u) {
  return __uint_as_float(((unsigned int)u) << 16);
}
__device__ __forceinline__ bf16 f2bf(float f) { return __float2bfloat16(f); }
__device__ __forceinline__ float sigmoidf_(float x) { return 1.0f / (1.0f + expf(-x)); }
__device__ __forceinline__ float softplusf_(float x) {
  return fmaxf(x, 0.0f) + log1pf(expf(-fabsf(x)));
}

// ---------------- K0: fused weight fp32->bf16 conversion (big weights) ------
__global__ __launch_bounds__(256) void cvt_weights_kernel(
    const float* __restrict__ s0, const float* __restrict__ s1,
    const float* __restrict__ s2, const float* __restrict__ s3,
    const float* __restrict__ s4, const float* __restrict__ s5,
    const float* __restrict__ s6,
    bf16* __restrict__ d0, bf16* __restrict__ d1, bf16* __restrict__ d2,
    bf16* __restrict__ d3, bf16* __restrict__ d4, bf16* __restrict__ d5,
    bf16* __restrict__ d6) {
  long i4 = (long)blockIdx.x * 256 + threadIdx.x;
  const float* s; bf16* d; long off;
  if (i4 < 32768) { s = s0; d = d0; off = i4; }
  else if (i4 < 294912) { s = s1; d = d1; off = i4 - 32768; }
  else if (i4 < 327680) { s = s2; d = d2; off = i4 - 294912; }
  else if (i4 < 360448) { s = s3; d = d3; off = i4 - 327680; }
  else if (i4 < 622592) { s = s4; d = d4; off = i4 - 360448; }
  else if (i4 < 884736) { s = s5; d = d5; off = i4 - 622592; }
  else { s = s6; d = d6; off = i4 - 884736; }
  float4 v = *(const float4*)(s + off * 4);
  d[off * 4 + 0] = f2bf(v.x);
  d[off * 4 + 1] = f2bf(v.y);
  d[off * 4 + 2] = f2bf(v.z);
  d[off * 4 + 3] = f2bf(v.w);
}

// ---------------- K0b: pack small LoRA-1 weights to bf16 --------------------
// wsk[32][1024]  = [tkw1(16) | mkw1(16)]
// wswa[96][1024] = [tdw1(64) | taw1(16) | maw1(16)]
__global__ __launch_bounds__(256) void cvt_small_kernel(
    const float* __restrict__ tkw1, const float* __restrict__ mkw1,
    const float* __restrict__ tdw1, const float* __restrict__ taw1,
    const float* __restrict__ maw1,
    bf16* __restrict__ wsk, bf16* __restrict__ wswa) {
  long i4 = (long)blockIdx.x * 256 + threadIdx.x;  // < 32768
  const float* s; bf16* d; long so, dof;
  if (i4 < 4096) { s = tkw1; so = i4; d = wsk; dof = i4; }
  else if (i4 < 8192) { s = mkw1; so = i4 - 4096; d = wsk; dof = i4; }
  else if (i4 < 24576) { s = tdw1; so = i4 - 8192; d = wswa; dof = i4 - 8192; }
  else if (i4 < 28672) { s = taw1; so = i4 - 24576; d = wswa; dof = i4 - 8192; }
  else { s = maw1; so = i4 - 28672; d = wswa; dof = i4 - 8192; }
  float4 v = *(const float4*)(s + so * 4);
  d[dof * 4 + 0] = f2bf(v.x);
  d[dof * 4 + 1] = f2bf(v.y);
  d[dof * 4 + 2] = f2bf(v.z);
  d[dof * 4 + 3] = f2bf(v.w);
}

// ---------------- K1: token shift (writes xx f32, xxx bf16) -----------------
__global__ __launch_bounds__(256) void shift_kernel(
    const float* __restrict__ x, const float* __restrict__ tmx,
    float* __restrict__ xx, bf16* __restrict__ xxxb) {
  long idx = (long)blockIdx.x * 256 + threadIdx.x;  // < B*T*C
  int c = (int)(idx & (C_ - 1));
  int t = (int)((idx >> 10) & (T_ - 1));
  float xv = x[idx];
  float xp = (t > 0) ? x[idx - C_] : 0.0f;
  float d = xp - xv;
  xx[idx] = d;
  xxxb[idx] = f2bf(xv + d * tmx[c]);
}

// ---------------- MFMA GEMM: C = A(bf16 MxK) * W^T (W bf16 NxK) -------------
// 64x64 block tile, 4 waves; BK=64 per barrier pair. N-guarded.
// actN: columns < actN get tanh.
__global__ __launch_bounds__(256) void gemm_mfma_kernel(
    const bf16* __restrict__ A, const bf16* __restrict__ W,
    float* __restrict__ Cf, bf16* __restrict__ Cb,
    int M, int N, int K, int actN) {
  __shared__ __align__(16) bf16 As[64][72];  // 144B row stride, 16B aligned
  __shared__ __align__(16) bf16 Ws[64][72];
  int tid = threadIdx.x;
  int m0 = blockIdx.y << 6, n0 = blockIdx.x << 6;
  int srow = tid >> 2, skg = (tid & 3) << 4;   // staging: row, 16 bf16 per thread
  int wv = tid >> 6, lane = tid & 63;
  int fr = lane & 15, fq = lane >> 4;
  f32x4 acc0 = {0.f, 0.f, 0.f, 0.f}, acc1 = acc0, acc2 = acc0, acc3 = acc0;
  bool wok = (n0 + srow) < N;
  const bf16* Ap = A + (long)(m0 + srow) * K + skg;
  const bf16* Wp = W + (long)(n0 + srow) * K + skg;
  short8 zz = {0, 0, 0, 0, 0, 0, 0, 0};
  for (int k0 = 0; k0 < K; k0 += 64) {
    *(short8*)&As[srow][skg] = *(const short8*)(Ap + k0);
    *(short8*)&As[srow][skg + 8] = *(const short8*)(Ap + k0 + 8);
    *(short8*)&Ws[srow][skg] = wok ? *(const short8*)(Wp + k0) : zz;
    *(short8*)&Ws[srow][skg + 8] = wok ? *(const short8*)(Wp + k0 + 8) : zz;
    __syncthreads();
#pragma unroll
    for (int kk = 0; kk < 2; kk++) {
      int ko = (fq << 3) + (kk << 5);
      short8 af = *(const short8*)&As[(wv << 4) + fr][ko];
      short8 b0 = *(const short8*)&Ws[fr][ko];
      short8 b1 = *(const short8*)&Ws[16 + fr][ko];
      short8 b2 = *(const short8*)&Ws[32 + fr][ko];
      short8 b3 = *(const short8*)&Ws[48 + fr][ko];
      acc0 = __builtin_amdgcn_mfma_f32_16x16x32_bf16(af, b0, acc0, 0, 0, 0);
      acc1 = __builtin_amdgcn_mfma_f32_16x16x32_bf16(af, b1, acc1, 0, 0, 0);
      acc2 = __builtin_amdgcn_mfma_f32_16x16x32_bf16(af, b2, acc2, 0, 0, 0);
      acc3 = __builtin_amdgcn_mfma_f32_16x16x32_bf16(af, b3, acc3, 0, 0, 0);
    }
    __syncthreads();
  }
  // C/D layout: col = lane&15, row = (lane>>4)*4 + reg
  int orow = m0 + (wv << 4) + (fq << 2);
  int ocol = n0 + fr;
  f32x4 av[4] = {acc0, acc1, acc2, acc3};
#pragma unroll
  for (int nt = 0; nt < 4; nt++) {
    int col = ocol + (nt << 4);
    if (col < N) {
#pragma unroll
      for (int r = 0; r < 4; r++) {
        float vvv = av[nt][r];
        if (col < actN) vvv = tanhf(vvv);
        long oi = (long)(orow + r) * N + col;
        if (Cb) Cb[oi] = f2bf(vvv); else Cf[oi] = vvv;
      }
    }
  }
}

// ---------------- K3: deltas + build xrg/xwa/xk/xv (bf16 out) ---------------
__global__ __launch_bounds__(256) void mix4_kernel(
    const float* __restrict__ x, const float* __restrict__ xx,
    const float* __restrict__ mix, const float* __restrict__ tmaa,
    const float* __restrict__ w2,
    bf16* __restrict__ xrg, bf16* __restrict__ xwa,
    bf16* __restrict__ xk, bf16* __restrict__ xv) {
  int m = blockIdx.x;
  int tid = threadIdx.x;
  __shared__ float mrow[128];
  if (tid < 128) mrow[tid] = mix[(long)m * 128 + tid];
  __syncthreads();
#pragma unroll
  for (int cc = 0; cc < 4; cc++) {
    int c = tid + (cc << 8);
    long off = (long)m * C_ + c;
    float xb = x[off];
    float xxv = xx[off];
    float res[4];
#pragma unroll
    for (int f = 0; f < 4; f++) {
      const float4* wp = (const float4*)(w2 + (((long)f * C_ + c) << 5));
      float dl = 0.f;
#pragma unroll
      for (int d4 = 0; d4 < 8; d4++) {
        float4 u = wp[d4];
        int db = (f << 5) + (d4 << 2);
        dl += mrow[db + 0] * u.x + mrow[db + 1] * u.y +
              mrow[db + 2] * u.z + mrow[db + 3] * u.w;
      }
      res[f] = xb + xxv * (tmaa[f * C_ + c] + dl);
    }
    xrg[off] = f2bf(res[0]); xwa[off] = f2bf(res[1]);
    xk[off] = f2bf(res[2]); xv[off] = f2bf(res[3]);
  }
}

// ---------------- K5: stage-2 small GEMMs + gates + per-head kk norm --------
// out1[m][32] = [kk1(tanh,16) | mk1(16)]; out2[m][96] = [w1(tanh,64)|a1(16)|ma1(16)]
__global__ __launch_bounds__(256) void fuse2_kernel(
    const float* __restrict__ kraw, const float* __restrict__ out1,
    const float* __restrict__ out2,
    const float* __restrict__ dw2, const float* __restrict__ kkw2,
    const float* __restrict__ aw2, const float* __restrict__ maw2,
    const float* __restrict__ mkw2,
    const float* __restrict__ tdec, const float* __restrict__ taa,
    const float* __restrict__ tma, const float* __restrict__ tmk,
    float* __restrict__ ew, float* __restrict__ kfin,
    float* __restrict__ kkn, float* __restrict__ bbo) {
  int m = blockIdx.x, tid = threadIdx.x;
  __shared__ float w1r[64], kk1r[16], a1r[16], ma1r[16], mk1r[16];
  if (tid < 64) w1r[tid] = out2[(long)m * 96 + tid];
  else if (tid < 80) kk1r[tid - 64] = out1[(long)m * 32 + (tid - 64)];
  else if (tid < 96) a1r[tid - 80] = out2[(long)m * 96 + 64 + (tid - 80)];
  else if (tid < 112) ma1r[tid - 96] = out2[(long)m * 96 + 80 + (tid - 96)];
  else if (tid < 128) mk1r[tid - 112] = out1[(long)m * 32 + 16 + (tid - 112)];
  __syncthreads();
  float kkp[4], av[4], wv[4], kr[4], mkv[4];
  float sumsq = 0.f;
#pragma unroll
  for (int j = 0; j < 4; j++) {
    int c = (tid << 2) + j;
    long off = (long)m * C_ + c;
    float wd = 0.f;
    const float4* dp = (const float4*)(dw2 + ((long)c << 6));
#pragma unroll
    for (int d4 = 0; d4 < 16; d4++) {
      float4 u = dp[d4];
      int db = d4 << 2;
      wd += w1r[db + 0] * u.x + w1r[db + 1] * u.y +
            w1r[db + 2] * u.z + w1r[db + 3] * u.w;
    }
    float w = -softplusf_(-(tdec[c] + wd)) - 0.5f;
    wv[j] = w;
    float kd = 0.f, ad = 0.f, mad = 0.f, mkd = 0.f;
    const float4* kp = (const float4*)(kkw2 + ((long)c << 4));
    const float4* ap = (const float4*)(aw2 + ((long)c << 4));
    const float4* mp = (const float4*)(maw2 + ((long)c << 4));
    const float4* qp = (const float4*)(mkw2 + ((long)c << 4));
#pragma unroll
    for (int d4 = 0; d4 < 4; d4++) {
      float4 u1 = kp[d4], u2 = ap[d4], u3 = mp[d4], u4 = qp[d4];
      int db = d4 << 2;
      kd += kk1r[db + 0] * u1.x + kk1r[db + 1] * u1.y +
            kk1r[db + 2] * u1.z + kk1r[db + 3] * u1.w;
      ad += a1r[db + 0] * u2.x + a1r[db + 1] * u2.y +
            a1r[db + 2] * u2.z + a1r[db + 3] * u2.w;
      mad += ma1r[db + 0] * u3.x + ma1r[db + 1] * u3.y +
             ma1r[db + 2] * u3.z + ma1r[db + 3] * u3.w;
      mkd += mk1r[db + 0] * u4.x + mk1r[db + 1] * u4.y +
             mk1r[db + 2] * u4.z + mk1r[db + 3] * u4.w;
    }
    float krw = kraw[off];
    float kkpre = krw + kd;
    kkp[j] = kkpre;
    sumsq += kkpre * kkpre;
    float a = sigmoidf_(taa[c] + ad);
    av[j] = a;
    float ma = sigmoidf_(tma[c] + mad);
    float mk = sigmoidf_(tmk[c] + mkd);
    mkv[j] = mk;
    kr[j] = krw * (ma + a * (1.f - ma));
  }
  sumsq += __shfl_xor(sumsq, 1);
  sumsq += __shfl_xor(sumsq, 2);
  sumsq += __shfl_xor(sumsq, 4);
  sumsq += __shfl_xor(sumsq, 8);
  float rn = 1.0f / fmaxf(sqrtf(sumsq), 1e-12f);
#pragma unroll
  for (int j = 0; j < 4; j++) {
    int c = (tid << 2) + j;
    long off = (long)m * C_ + c;
    float kknv = kkp[j] * rn;
    kkn[off] = kknv;
    bbo[off] = -kknv * av[j];
    ew[off] = expf(wv[j]);
    kfin[off] = kr[j] * expf(wv[j] * mkv[j]);
  }
}

// ---------------- K6: RWKV-7 scan, quad-shuffle layout ----------------------
// 128 blocks x 64 threads. block = (b,h,rowgroup of 16). lane=(r<<2)|q:
// row = rg*16 + r, lane holds 16 consecutive keys [q*16, q*16+16).
// Reductions across q only: shfl_xor 1,2 = DPP quad_perm (fast).
__global__ __launch_bounds__(64) void scan_kernel(
    const float* __restrict__ rB, const float* __restrict__ ewB,
    const float* __restrict__ kB, const float* __restrict__ vB,
    const float* __restrict__ kkB, const float* __restrict__ bbB,
    float* __restrict__ yB) {
  int bid = blockIdx.x;          // 0..127
  int bh = bid >> 2;             // 0..31
  int rg = bid & 3;
  int b = bh >> 4, h = bh & 15;
  int lane = threadIdx.x;
  int r = lane >> 2, q = lane & 3;
  int row = (rg << 4) + r;
  int kq = q << 4;
  const long base = ((long)b * T_) * C_ + (h << 6);
  float S[16];
#pragma unroll
  for (int j = 0; j < 16; j++) S[j] = 0.f;
  float4 kk4[2][4], ew4[2][4], k4[2][4], bb4[2][4], r4[2][4];
  float v2[2];
#pragma unroll
  for (int i = 0; i < 2; i++) {
    long o = base + (long)i * C_ + kq;
#pragma unroll
    for (int jj = 0; jj < 4; jj++) {
      kk4[i][jj] = *(const float4*)(kkB + o + jj * 4);
      ew4[i][jj] = *(const float4*)(ewB + o + jj * 4);
      k4[i][jj] = *(const float4*)(kB + o + jj * 4);
      bb4[i][jj] = *(const float4*)(bbB + o + jj * 4);
      r4[i][jj] = *(const float4*)(rB + o + jj * 4);
    }
    v2[i] = vB[base + (long)i * C_ + row];
  }
  for (int t = 0; t < T_; t += 2) {
#pragma unroll
    for (int s = 0; s < 2; s++) {
      int tt = t + s;
      const float* ckk = (const float*)&kk4[s][0];
      const float* cew = (const float*)&ew4[s][0];
      const float* ck = (const float*)&k4[s][0];
      const float* cbb = (const float*)&bb4[s][0];
      const float* crr = (const float*)&r4[s][0];
      float cv = v2[s];
      // sab partial over 16 keys (4 independent chains)
      float p0 = 0, p1 = 0, p2 = 0, p3 = 0;
#pragma unroll
      for (int j = 0; j < 4; j++) {
        p0 += S[j] * ckk[j];
        p1 += S[4 + j] * ckk[4 + j];
        p2 += S[8 + j] * ckk[8 + j];
        p3 += S[12 + j] * ckk[12 + j];
      }
      float sab = (p0 + p1) + (p2 + p3);
      sab += __shfl_xor(sab, 1);
      sab += __shfl_xor(sab, 2);
      // state update + y partial
#pragma unroll
      for (int j = 0; j < 16; j++)
        S[j] = S[j] * cew[j] + sab * cbb[j] + cv * ck[j];
      float y0 = 0, y1 = 0, y2 = 0, y3 = 0;
#pragma unroll
      for (int j = 0; j < 4; j++) {
        y0 += S[j] * crr[j];
        y1 += S[4 + j] * crr[4 + j];
        y2 += S[8 + j] * crr[8 + j];
        y3 += S[12 + j] * crr[12 + j];
      }
      float y = (y0 + y1) + (y2 + y3);
      y += __shfl_xor(y, 1);
      y += __shfl_xor(y, 2);
      if (q == 0) yB[base + (long)tt * C_ + row] = y;
      // prefetch tt+2 into slot s
      int tl = tt + 2; if (tl > T_ - 1) tl = T_ - 1;
      long o = base + (long)tl * C_ + kq;
#pragma unroll
      for (int jj = 0; jj < 4; jj++) {
        kk4[s][jj] = *(const float4*)(kkB + o + jj * 4);
        ew4[s][jj] = *(const float4*)(ewB + o + jj * 4);
        k4[s][jj] = *(const float4*)(kB + o + jj * 4);
        bb4[s][jj] = *(const float4*)(bbB + o + jj * 4);
        r4[s][jj] = *(const float4*)(rB + o + jj * 4);
      }
      v2[s] = vB[base + (long)tl * C_ + row];
    }
  }
}

// ---------------- K7: GroupNorm + bonus + gate (bf16 out) -------------------
__global__ __launch_bounds__(256) void gnout_kernel(
    const float* __restrict__ y, const float* __restrict__ r,
    const float* __restrict__ kf, const float* __restrict__ v,
    const float* __restrict__ g,
    const float* __restrict__ lnw, const float* __restrict__ lnb,
    const float* __restrict__ fa, bf16* __restrict__ z) {
  int tid = threadIdx.x;
  int w = tid >> 6, lane = tid & 63;
  int gi = (blockIdx.x << 2) + w;  // (b*T+t)*H + h
  int h = gi & 15, mt = gi >> 4;
  long off = (long)mt * C_ + (h << 6) + lane;
  float yv = y[off];
  float s = yv;
  s += __shfl_xor(s, 1); s += __shfl_xor(s, 2); s += __shfl_xor(s, 4);
  s += __shfl_xor(s, 8); s += __shfl_xor(s, 16); s += __shfl_xor(s, 32);
  float mu = s * (1.0f / 64.0f);
  float d = yv - mu;
  float s2 = d * d;
  s2 += __shfl_xor(s2, 1); s2 += __shfl_xor(s2, 2); s2 += __shfl_xor(s2, 4);
  s2 += __shfl_xor(s2, 8); s2 += __shfl_xor(s2, 16); s2 += __shfl_xor(s2, 32);
  float var = s2 * (1.0f / 64.0f);
  int hc = (h << 6) + lane;
  float dot = r[off] * kf[off] * fa[hc];
  dot += __shfl_xor(dot, 1); dot += __shfl_xor(dot, 2); dot += __shfl_xor(dot, 4);
  dot += __shfl_xor(dot, 8); dot += __shfl_xor(dot, 16); dot += __shfl_xor(dot, 32);
  float yn = d * rsqrtf(var + 0.00064f) * lnw[hc] + lnb[hc];
  z[off] = f2bf((yn + dot * v[off]) * g[off]);
}

extern "C" void kernel_launch(void* const* d_in, const int* in_sizes, int n_in,
                              void* d_out, int out_size, void* d_ws, size_t ws_size,
                              hipStream_t stream) {
  const float* x = (const float*)d_in[0];
  const float* tmx = (const float*)d_in[1];
  const float* tmaa = (const float*)d_in[2];
  const float* tmw1 = (const float*)d_in[3];
  const float* tmw2 = (const float*)d_in[4];
  const float* tdec = (const float*)d_in[5];
  const float* tdw1 = (const float*)d_in[6];
  const float* tdw2 = (const float*)d_in[7];
  const float* taa5 = (const float*)d_in[8];
  const float* taw1 = (const float*)d_in[9];
  const float* taw2 = (const float*)d_in[10];
  const float* tkw1 = (const float*)d_in[11];
  const float* tkw2 = (const float*)d_in[12];
  const float* gw1 = (const float*)d_in[13];
  const float* gw2 = (const float*)d_in[14];
  const float* tmia = (const float*)d_in[15];
  const float* maw1 = (const float*)d_in[16];
  const float* maw2 = (const float*)d_in[17];
  const float* tmik = (const float*)d_in[18];
  const float* mkw1 = (const float*)d_in[19];
  const float* mkw2 = (const float*)d_in[20];
  const float* wrec = (const float*)d_in[21];
  const float* wkey = (const float*)d_in[22];
  const float* wval = (const float*)d_in[23];
  const float* wout = (const float*)d_in[24];
  const float* lnw = (const float*)d_in[25];
  const float* lnb = (const float*)d_in[26];
  const float* faaa = (const float*)d_in[27];

  const long MT = 2048, CC = 1024;
  char* base = (char*)d_ws;
  float* xx = (float*)base;    base += MT * CC * 4;   // also y
  bf16* xxxb = (bf16*)base;    base += MT * CC * 2;
  bf16* xrgb = (bf16*)base;    base += MT * CC * 2;   // ┐ kfin overlays (8MB)
  bf16* xwab = (bf16*)base;    base += MT * CC * 2;   // ┘
  bf16* xkb = (bf16*)base;     base += MT * CC * 2;   // ┐ kkn overlays (8MB)
  bf16* xvb = (bf16*)base;     base += MT * CC * 2;   // ┘
  float* rr = (float*)base;    base += MT * CC * 4;
  float* kraw = (float*)base;  base += MT * CC * 4;   // also ew
  float* vv = (float*)base;    base += MT * CC * 4;
  float* gg = (float*)base;    base += MT * CC * 4;
  float* bbo = (float*)base;   base += MT * CC * 4;
  float* mix = (float*)base;   base += MT * 128 * 4;
  bf16* g1b = (bf16*)base;     base += MT * 128 * 2;
  float* out1 = (float*)base;  base += MT * 32 * 4;   // [kk1|mk1]
  float* out2 = (float*)base;  base += MT * 96 * 4;   // [w1|a1|ma1]
  bf16* zb = (bf16*)base;      base += MT * CC * 2;
  bf16* tmw1b = (bf16*)base;   base += 128 * CC * 2;
  bf16* wrecb = (bf16*)base;   base += CC * CC * 2;
  bf16* gw1b = (bf16*)base;    base += 128 * CC * 2;
  bf16* gw2b = (bf16*)base;    base += CC * 128 * 2;
  bf16* wkeyb = (bf16*)base;   base += CC * CC * 2;
  bf16* wvalb = (bf16*)base;   base += CC * CC * 2;
  bf16* woutb = (bf16*)base;   base += CC * CC * 2;
  bf16* wskb = (bf16*)base;    base += 32 * CC * 2;
  bf16* wswab = (bf16*)base;   base += 96 * CC * 2;
  // aliases (dead-buffer reuse, verified non-overlapping in time):
  float* ew = kraw;            // fuse2 reads kraw then writes ew at same offs
  float* kfin = (float*)xrgb;  // xrg/xwa bf16 dead before fuse2
  float* kkn = (float*)xkb;    // xk/xv bf16 dead before fuse2
  float* y = xx;               // xx dead after mix4

  auto gemm_m = [&](const bf16* A, const bf16* W, float* Cf, bf16* Cb,
                    int M, int N, int K, int actN) {
    dim3 grid((N + 63) / 64, M / 64);
    gemm_mfma_kernel<<<grid, 256, 0, stream>>>(A, W, Cf, Cb, M, N, K, actN);
  };

  cvt_weights_kernel<<<4480, 256, 0, stream>>>(
      tmw1, wrec, gw1, gw2, wkey, wval, wout,
      tmw1b, wrecb, gw1b, gw2b, wkeyb, wvalb, woutb);
  cvt_small_kernel<<<128, 256, 0, stream>>>(tkw1, mkw1, tdw1, taw1, maw1,
                                            wskb, wswab);
  shift_kernel<<<8192, 256, 0, stream>>>(x, tmx, xx, xxxb);
  gemm_m(xxxb, tmw1b, mix, nullptr, 2048, 128, 1024, 128);   // tanh all
  mix4_kernel<<<2048, 256, 0, stream>>>(x, xx, mix, tmaa, tmw2,
                                        xrgb, xwab, xkb, xvb);
  gemm_m(xrgb, wrecb, rr, nullptr, 2048, 1024, 1024, 0);
  gemm_m(xrgb, gw1b, nullptr, g1b, 2048, 128, 1024, 128);    // tanh all
  gemm_m(g1b, gw2b, gg, nullptr, 2048, 1024, 128, 0);
  gemm_m(xkb, wkeyb, kraw, nullptr, 2048, 1024, 1024, 0);
  gemm_m(xkb, wskb, out1, nullptr, 2048, 32, 1024, 16);      // tanh cols<16
  gemm_m(xvb, wvalb, vv, nullptr, 2048, 1024, 1024, 0);
  gemm_m(xwab, wswab, out2, nullptr, 2048, 96, 1024, 64);    // tanh cols<64
  fuse2_kernel<<<2048, 256, 0, stream>>>(kraw, out1, out2,
                                         tdw2, tkw2, taw2, maw2, mkw2,
                                         tdec, taa5, tmia, tmik,
                                         ew, kfin, kkn, bbo);
  scan_kernel<<<128, 64, 0, stream>>>(rr, ew, kfin, vv, kkn, bbo, y);
  gnout_kernel<<<8192, 256, 0, stream>>>(y, rr, kfin, vv, gg, lnw, lnb, faaa, zb);
  gemm_m(zb, woutb, (float*)d_out, nullptr, 2048, 1024, 1024, 0);
}